// Round 1
// baseline (382.843 us; speedup 1.0000x reference)
//
#include <hip/hip_runtime.h>
#include <hip/hip_fp16.h>
#include <math.h>

// GCN 2-layer (DGL GraphConv norm='both'). CSR built by a two-level MSD
// counting sort with NO per-edge global atomics.
//   A : per-block LDS hist of dst>>8 and src>>8 (+38k tiny global adds)
//       co-scheduled with featw1 = fp16(feat @ W1), UNNORMALIZED.
//       featw1: W1 column held in 64 VGPRs per lane (no LDS, no barriers),
//       16 rows/wave, 2-row unroll -> 782 blocks instead of 12500.
//   C0: 1-block exclusive scan of the 196 bin counts -> bases + cursors
//   B : partition: edges scattered by dst-high (packed src|dstLow<<17, LDS ranks,
//       per-block range reserve), src-low bytes scattered by src-high
//   D : per 256-node bin: LDS hist of low byte -> in_deg, row_start, csr_src
//       scatter; src bins -> out_deg AND pre-scale featp rows by
//       rsqrt(out_deg) (removes per-edge out_deg gather + rsqrt from agg1)
//   agg1: one wave/node, 8 edge-groups x 8 fp16 chunks, unroll-2; features
//         already out_norm-scaled; relu+b1+.W2 epilogue -> s_buf
//   agg2: 16 lanes/node -> sigmoid -> out
// Requires N <= 65536 (src packed into 17 bits, NB <= 256). N=50000 here.

#define BS 256
#define EPB 4096   // edges per partition block (16 iters of 256)

// ---- A: bin histograms + featw1 (independent work co-scheduled) ----
__global__ void histA_featw1_kernel(const int* __restrict__ src, const int* __restrict__ dst,
                                    const float* __restrict__ feat, const float* __restrict__ W1,
                                    int* __restrict__ dstBinCount, int* __restrict__ srcBinCount,
                                    __half* __restrict__ featp,
                                    int E, int N, int NB, int T) {
    __shared__ int histD[256];
    __shared__ int histS[256];
    int tid = threadIdx.x;
    if ((int)blockIdx.x < T) {
        histD[tid] = 0; histS[tid] = 0;
        __syncthreads();
        int base = blockIdx.x * EPB;
        #pragma unroll
        for (int it = 0; it < EPB / BS; it++) {
            int e = base + it * BS + tid;
            if (e < E) {
                atomicAdd(&histD[dst[e] >> 8], 1);
                atomicAdd(&histS[src[e] >> 8], 1);
            }
        }
        __syncthreads();
        if (tid < NB) {
            if (histD[tid]) atomicAdd(&dstBinCount[tid], histD[tid]);
            if (histS[tid]) atomicAdd(&srcBinCount[tid], histS[tid]);
        }
    } else {
        int wave = tid >> 6, lane = tid & 63;
        // W1 column for this lane lives in registers (fully unrolled -> no scratch)
        float w[64];
        #pragma unroll
        for (int k = 0; k < 64; k++) w[k] = W1[k * 64 + lane];   // coalesced, L2-hot
        int rowBase = ((int)blockIdx.x - T) * 64 + wave * 16;    // 16 rows per wave
        #pragma unroll
        for (int rr = 0; rr < 16; rr += 2) {
            int row0 = rowBase + rr;
            int row1 = row0 + 1;
            // clamp (only last block partial) so loads stay unguarded
            const float4* f0 = (const float4*)(feat + (size_t)min(row0, N - 1) * 64);
            const float4* f1 = (const float4*)(feat + (size_t)min(row1, N - 1) * 64);
            float a0 = 0, a1 = 0, a2 = 0, a3 = 0;
            float c0 = 0, c1 = 0, c2 = 0, c3 = 0;
            #pragma unroll
            for (int k4 = 0; k4 < 16; k4++) {
                float4 x = f0[k4];     // wave-uniform broadcast load
                float4 y = f1[k4];
                a0 += x.x * w[4 * k4 + 0]; a1 += x.y * w[4 * k4 + 1];
                a2 += x.z * w[4 * k4 + 2]; a3 += x.w * w[4 * k4 + 3];
                c0 += y.x * w[4 * k4 + 0]; c1 += y.y * w[4 * k4 + 1];
                c2 += y.z * w[4 * k4 + 2]; c3 += y.w * w[4 * k4 + 3];
            }
            if (row0 < N) featp[(size_t)row0 * 64 + lane] = __float2half((a0 + a1) + (a2 + a3));
            if (row1 < N) featp[(size_t)row1 * 64 + lane] = __float2half((c0 + c1) + (c2 + c3));
        }
    }
}

// ---- C0: scan both 196-bin count arrays (tiny, 1 block) ----
__global__ void scan_bins_kernel(const int* __restrict__ dstBinCount, const int* __restrict__ srcBinCount,
                                 int* __restrict__ dstBinBase, int* __restrict__ srcBinBase,
                                 int* __restrict__ dstCursor, int* __restrict__ srcCursor, int NB) {
    __shared__ int s[256];
    int t = threadIdx.x;
    int v = (t < NB) ? dstBinCount[t] : 0;
    s[t] = v; __syncthreads();
    for (int off = 1; off < 256; off <<= 1) {
        int u = (t >= off) ? s[t - off] : 0; __syncthreads();
        s[t] += u; __syncthreads();
    }
    if (t < NB) {
        int ex = s[t] - v;
        dstBinBase[t] = ex; dstCursor[t] = ex;
        if (t == NB - 1) dstBinBase[NB] = s[t];
    }
    __syncthreads();
    v = (t < NB) ? srcBinCount[t] : 0;
    s[t] = v; __syncthreads();
    for (int off = 1; off < 256; off <<= 1) {
        int u = (t >= off) ? s[t - off] : 0; __syncthreads();
        s[t] += u; __syncthreads();
    }
    if (t < NB) {
        int ex = s[t] - v;
        srcBinBase[t] = ex; srcCursor[t] = ex;
        if (t == NB - 1) srcBinBase[NB] = s[t];
    }
}

// ---- B: partition edges by dst>>8 and src-lows by src>>8 (LDS ranks) ----
__global__ void partition_kernel(const int* __restrict__ src, const int* __restrict__ dst,
                                 int* __restrict__ dstCursor, int* __restrict__ srcCursor,
                                 int* __restrict__ packed, int* __restrict__ srcPart,
                                 int E, int NB) {
    __shared__ int arr[256];
    int tid = threadIdx.x;
    int base = blockIdx.x * EPB;
    // dst partition
    arr[tid] = 0; __syncthreads();
    #pragma unroll
    for (int it = 0; it < EPB / BS; it++) {
        int e = base + it * BS + tid;
        if (e < E) atomicAdd(&arr[dst[e] >> 8], 1);
    }
    __syncthreads();
    int h = arr[tid];
    int rb = (tid < NB && h) ? atomicAdd(&dstCursor[tid], h) : 0;
    __syncthreads();
    arr[tid] = rb;
    __syncthreads();
    #pragma unroll
    for (int it = 0; it < EPB / BS; it++) {
        int e = base + it * BS + tid;
        if (e < E) {
            int d = dst[e], s2 = src[e];
            int pos = atomicAdd(&arr[d >> 8], 1);
            packed[pos] = s2 | ((d & 255) << 17);
        }
    }
    __syncthreads();
    // src partition (for out_deg counting)
    arr[tid] = 0; __syncthreads();
    #pragma unroll
    for (int it = 0; it < EPB / BS; it++) {
        int e = base + it * BS + tid;
        if (e < E) atomicAdd(&arr[src[e] >> 8], 1);
    }
    __syncthreads();
    h = arr[tid];
    rb = (tid < NB && h) ? atomicAdd(&srcCursor[tid], h) : 0;
    __syncthreads();
    arr[tid] = rb;
    __syncthreads();
    #pragma unroll
    for (int it = 0; it < EPB / BS; it++) {
        int e = base + it * BS + tid;
        if (e < E) {
            int s2 = src[e];
            int pos = atomicAdd(&arr[s2 >> 8], 1);
            srcPart[pos] = s2 & 255;
        }
    }
}

// ---- D: per-bin finalize: in_deg/row_start/csr_src (dst bins);
//          out_deg + featp out_norm pre-scale (src bins) ----
__global__ void finalize_kernel(const int* __restrict__ dstBinBase, const int* __restrict__ srcBinBase,
                                const int* __restrict__ packed, const int* __restrict__ srcPart,
                                int* __restrict__ csr_src, int* __restrict__ in_deg,
                                int* __restrict__ row_start, int* __restrict__ out_deg,
                                __half* __restrict__ featp,
                                int N, int NB) {
    __shared__ int hist[256];
    __shared__ int sc[256];
    int tid = threadIdx.x;
    int b = blockIdx.x;
    if (b < NB) {
        int lo = dstBinBase[b], hi = dstBinBase[b + 1];
        hist[tid] = 0; __syncthreads();
        for (int i = lo + tid; i < hi; i += BS)
            atomicAdd(&hist[(packed[i] >> 17) & 255], 1);
        __syncthreads();
        int v = hist[tid];
        sc[tid] = v; __syncthreads();
        for (int off = 1; off < 256; off <<= 1) {
            int u = (tid >= off) ? sc[tid - off] : 0; __syncthreads();
            sc[tid] += u; __syncthreads();
        }
        int ex = sc[tid] - v;          // exclusive within bin
        int n = b * 256 + tid;
        if (n < N) { in_deg[n] = v; row_start[n] = lo + ex; }
        sc[tid] = lo + ex;             // becomes the scatter cursor
        __syncthreads();
        for (int i = lo + tid; i < hi; i += BS) {
            int pv = packed[i];
            int pos = atomicAdd(&sc[(pv >> 17) & 255], 1);
            csr_src[pos] = pv & 0x1FFFF;
        }
    } else {
        int sb = b - NB;
        int lo = srcBinBase[sb], hi = srcBinBase[sb + 1];
        hist[tid] = 0; __syncthreads();
        for (int i = lo + tid; i < hi; i += BS)
            atomicAdd(&hist[srcPart[i]], 1);
        __syncthreads();
        int n = sb * 256 + tid;
        int od = hist[tid];
        if (n < N) out_deg[n] = od;
        float* snorm = (float*)sc;     // reuse LDS
        snorm[tid] = rsqrtf(fmaxf((float)od, 1.0f));
        __syncthreads();
        // pre-scale featp rows of this bin by out_norm (contiguous 32KB block)
        int nodes = min(256, N - sb * 256);
        uint4* fp = (uint4*)(featp + (size_t)sb * 256 * 64);   // 8 uint4 per row
        int total = nodes * 8;
        for (int i = tid; i < total; i += BS) {
            float s = snorm[i >> 3];   // 8 lanes share a node -> LDS broadcast
            uint4 u = fp[i];
            __half2* hh = (__half2*)&u;
            #pragma unroll
            for (int c = 0; c < 4; c++) {
                float2 p = __half22float2(hh[c]);
                p.x *= s; p.y *= s;
                hh[c] = __float22half2_rn(p);
            }
            fp[i] = u;
        }
    }
}

// ---- agg1: one wave/node; 8 edge-groups x 8 chunks, unroll-2; featp pre-scaled ----
__global__ void csr_agg1_kernel(const int* __restrict__ row_start, const int* __restrict__ in_deg,
                                const int* __restrict__ csr_src, const int* __restrict__ out_deg,
                                const __half* __restrict__ featp,
                                const float* __restrict__ b1, const float* __restrict__ W2,
                                float* __restrict__ s_buf, int N) {
    int gid = blockIdx.x * blockDim.x + threadIdx.x;
    int n = gid >> 6;
    if (n >= N) return;
    int lane = threadIdx.x & 63;
    int g = lane >> 3;   // edge slot within batch of 8
    int l = lane & 7;    // feature chunk: features [8l, 8l+8)
    int start = row_start[n];
    int deg = in_deg[n];
    float acc[8] = {0, 0, 0, 0, 0, 0, 0, 0};
    const uint4* fp4 = (const uint4*)featp;
    for (int j = 0; j < deg; j += 16) {
        int e0 = j + g;
        int e1 = j + 8 + g;
        bool p0 = e0 < deg;
        bool p1 = e1 < deg;
        int sn0 = p0 ? csr_src[start + e0] : 0;
        int sn1 = p1 ? csr_src[start + e1] : 0;
        uint4 q0 = {0, 0, 0, 0}, q1 = {0, 0, 0, 0};
        if (p0) q0 = fp4[(size_t)sn0 * 8 + l];
        if (p1) q1 = fp4[(size_t)sn1 * 8 + l];
        const __half2* h0 = (const __half2*)&q0;
        const __half2* h1 = (const __half2*)&q1;
        #pragma unroll
        for (int c = 0; c < 4; c++) {
            float2 f0 = __half22float2(h0[c]);
            float2 f1 = __half22float2(h1[c]);
            acc[2 * c]     += f0.x + f1.x;
            acc[2 * c + 1] += f0.y + f1.y;
        }
    }
    #pragma unroll
    for (int off = 8; off < 64; off <<= 1) {
        #pragma unroll
        for (int c = 0; c < 8; c++)
            acc[c] += __shfl_xor(acc[c], off, 64);
    }
    float inn = rsqrtf(fmaxf((float)deg, 1.0f));
    float v = 0.0f;
    #pragma unroll
    for (int c = 0; c < 8; c++) {
        float h = fmaxf(inn * acc[c] + b1[l * 8 + c], 0.0f);
        v += h * W2[l * 8 + c];
    }
    #pragma unroll
    for (int off = 1; off < 8; off <<= 1)
        v += __shfl_xor(v, off, 64);
    if (lane == 0)
        s_buf[n] = rsqrtf(fmaxf((float)out_deg[n], 1.0f)) * v;
}

// ---- agg2: 16 lanes/node, unroll-2, sigmoid -> out ----
__global__ void csr_agg2_kernel(const int* __restrict__ row_start, const int* __restrict__ in_deg,
                                const int* __restrict__ csr_src,
                                const float* __restrict__ s_buf, const float* __restrict__ b2,
                                float* __restrict__ out, int N) {
    int gid = blockIdx.x * blockDim.x + threadIdx.x;
    int n = gid >> 4;
    if (n >= N) return;
    int sub = gid & 15;
    int start = row_start[n];
    int deg = in_deg[n];
    float a = 0.0f;
    for (int j = sub; j < deg; j += 32) {
        int j1 = j + 16;
        int i0 = csr_src[start + j];
        int i1 = (j1 < deg) ? csr_src[start + j1] : 0;
        float v0 = s_buf[i0];
        float v1 = (j1 < deg) ? s_buf[i1] : 0.0f;
        a += v0 + v1;
    }
    #pragma unroll
    for (int off = 1; off < 16; off <<= 1)
        a += __shfl_xor(a, off, 64);
    if (sub == 0) {
        float x = rsqrtf(fmaxf((float)deg, 1.0f)) * a + b2[0];
        out[n] = 1.0f / (1.0f + expf(-x));
    }
}

extern "C" void kernel_launch(void* const* d_in, const int* in_sizes, int n_in,
                              void* d_out, int out_size, void* d_ws, size_t ws_size,
                              hipStream_t stream) {
    const float* feat = (const float*)d_in[0];
    const float* W1   = (const float*)d_in[1];
    const float* b1   = (const float*)d_in[2];
    const float* W2   = (const float*)d_in[3];
    const float* b2   = (const float*)d_in[4];
    const int* src = (const int*)d_in[5];
    const int* dst = (const int*)d_in[6];
    float* out = (float*)d_out;

    const int N  = in_sizes[0] / 64;       // 50000
    const int E  = in_sizes[5];            // 800000
    const int NB = (N + 255) >> 8;         // 196 bins of 256 nodes
    const int T  = (E + EPB - 1) / EPB;    // 196 partition blocks

    // workspace: int region | fp16 featp (16B-aligned) | float s_buf
    int* wsi = (int*)d_ws;
    int* dstBinCount = wsi;                          // NB  (zeroed together)
    int* srcBinCount = dstBinCount + NB;             // NB
    int* dstBinBase  = srcBinCount + NB;             // NB+1
    int* srcBinBase  = dstBinBase + NB + 1;          // NB+1
    int* dstCursor   = srcBinBase + NB + 1;          // NB
    int* srcCursor   = dstCursor + NB;               // NB
    int* in_deg      = srcCursor + NB;               // N
    int* row_start   = in_deg + N;                   // N
    int* out_deg     = row_start + N;                // N
    int* packed      = out_deg + N;                  // E
    int* srcPart     = packed + E;                   // E
    int* csr_src     = srcPart + E;                  // E
    size_t int_bytes = ((size_t)(6 * NB + 2) + 3 * (size_t)N + 3 * (size_t)E) * sizeof(int);
    size_t half_off  = (int_bytes + 15) & ~(size_t)15;
    __half* featp = (__half*)((char*)d_ws + half_off);            // 64N fp16
    float* s_buf  = (float*)((char*)d_ws + half_off + (size_t)64 * N * sizeof(__half));

    hipMemsetAsync(dstBinCount, 0, (size_t)2 * NB * sizeof(int), stream);

    histA_featw1_kernel<<<T + (N + 63) / 64, BS, 0, stream>>>(
        src, dst, feat, W1, dstBinCount, srcBinCount, featp, E, N, NB, T);
    scan_bins_kernel<<<1, 256, 0, stream>>>(
        dstBinCount, srcBinCount, dstBinBase, srcBinBase, dstCursor, srcCursor, NB);
    partition_kernel<<<T, BS, 0, stream>>>(
        src, dst, dstCursor, srcCursor, packed, srcPart, E, NB);
    finalize_kernel<<<2 * NB, BS, 0, stream>>>(
        dstBinBase, srcBinBase, packed, srcPart, csr_src, in_deg, row_start, out_deg, featp, N, NB);
    csr_agg1_kernel<<<(int)(((size_t)N * 64 + BS - 1) / BS), BS, 0, stream>>>(
        row_start, in_deg, csr_src, out_deg, featp, b1, W2, s_buf, N);
    csr_agg2_kernel<<<(int)(((size_t)N * 16 + BS - 1) / BS), BS, 0, stream>>>(
        row_start, in_deg, csr_src, s_buf, b2, out, N);
}

// Round 2
// 277.201 us; speedup vs baseline: 1.3811x; 1.3811x over previous
//
#include <hip/hip_runtime.h>
#include <hip/hip_fp16.h>
#include <math.h>

// GCN 2-layer (DGL GraphConv norm='both'). CSR built by a two-level MSD
// counting sort with NO per-edge global atomics.
//   A : per-block LDS hist of dst>>8 and src>>8 (+38k tiny global adds)
//       co-scheduled with featw1 = fp16(feat @ W1), UNNORMALIZED.
//       featw1: W1 staged in LDS ONCE per block (16KB), 4 waves x 16 rows
//       = 64 rows/block -> 782 blocks; 2-row unroll shares each LDS w-read.
//       (round-1 register-resident w[64] spilled to scratch: VGPR capped 64,
//       670MB scratch traffic, 237us. LDS pattern is proven conflict-free.)
//   C0: 1-block exclusive scan of the 196 bin counts -> bases + cursors
//   B : partition: edges scattered by dst-high (packed src|dstLow<<17, LDS ranks,
//       per-block range reserve), src-low bytes scattered by src-high
//   D : per 256-node bin: LDS hist of low byte -> in_deg, row_start, csr_src
//       scatter; src bins -> out_deg AND pre-scale featp rows by
//       rsqrt(out_deg) (removes per-edge out_deg gather + rsqrt from agg1)
//   agg1: one wave/node, 8 edge-groups x 8 fp16 chunks, unroll-2; features
//         already out_norm-scaled; relu+b1+.W2 epilogue -> s_buf
//   agg2: 16 lanes/node -> sigmoid -> out
// Requires N <= 65536 (src packed into 17 bits, NB <= 256). N=50000 here.

#define BS 256
#define EPB 4096   // edges per partition block (16 iters of 256)

// ---- A: bin histograms + featw1 (independent work co-scheduled) ----
__global__ void histA_featw1_kernel(const int* __restrict__ src, const int* __restrict__ dst,
                                    const float* __restrict__ feat, const float* __restrict__ W1,
                                    int* __restrict__ dstBinCount, int* __restrict__ srcBinCount,
                                    __half* __restrict__ featp,
                                    int E, int N, int NB, int T) {
    __shared__ float w[64 * 64];
    __shared__ int histD[256];
    __shared__ int histS[256];
    int tid = threadIdx.x;
    if ((int)blockIdx.x < T) {
        histD[tid] = 0; histS[tid] = 0;
        __syncthreads();
        int base = blockIdx.x * EPB;
        #pragma unroll
        for (int it = 0; it < EPB / BS; it++) {
            int e = base + it * BS + tid;
            if (e < E) {
                atomicAdd(&histD[dst[e] >> 8], 1);
                atomicAdd(&histS[src[e] >> 8], 1);
            }
        }
        __syncthreads();
        if (tid < NB) {
            if (histD[tid]) atomicAdd(&dstBinCount[tid], histD[tid]);
            if (histS[tid]) atomicAdd(&srcBinCount[tid], histS[tid]);
        }
    } else {
        // stage W1 once per block
        for (int i = tid; i < 64 * 16; i += BS)
            ((float4*)w)[i] = ((const float4*)W1)[i];
        __syncthreads();
        int wave = tid >> 6, lane = tid & 63;
        int rowBase = ((int)blockIdx.x - T) * 64 + wave * 16;   // 16 rows per wave
        #pragma unroll 1
        for (int rr = 0; rr < 16; rr += 2) {
            int row0 = rowBase + rr;
            int row1 = row0 + 1;
            // clamp (only last block partial) so loads stay unguarded
            const float4* f0 = (const float4*)(feat + (size_t)min(row0, N - 1) * 64);
            const float4* f1 = (const float4*)(feat + (size_t)min(row1, N - 1) * 64);
            float a0 = 0, a1 = 0, a2 = 0, a3 = 0;
            float c0 = 0, c1 = 0, c2 = 0, c3 = 0;
            #pragma unroll
            for (int k4 = 0; k4 < 16; k4++) {
                float4 x = f0[k4];                         // wave-uniform broadcast
                float4 y = f1[k4];
                float w0 = w[(4 * k4 + 0) * 64 + lane];    // lane stride-1: conflict-free,
                float w1 = w[(4 * k4 + 1) * 64 + lane];    // shared by both rows
                float w2 = w[(4 * k4 + 2) * 64 + lane];
                float w3 = w[(4 * k4 + 3) * 64 + lane];
                a0 += x.x * w0; a1 += x.y * w1; a2 += x.z * w2; a3 += x.w * w3;
                c0 += y.x * w0; c1 += y.y * w1; c2 += y.z * w2; c3 += y.w * w3;
            }
            if (row0 < N) featp[(size_t)row0 * 64 + lane] = __float2half((a0 + a1) + (a2 + a3));
            if (row1 < N) featp[(size_t)row1 * 64 + lane] = __float2half((c0 + c1) + (c2 + c3));
        }
    }
}

// ---- C0: scan both 196-bin count arrays (tiny, 1 block) ----
__global__ void scan_bins_kernel(const int* __restrict__ dstBinCount, const int* __restrict__ srcBinCount,
                                 int* __restrict__ dstBinBase, int* __restrict__ srcBinBase,
                                 int* __restrict__ dstCursor, int* __restrict__ srcCursor, int NB) {
    __shared__ int s[256];
    int t = threadIdx.x;
    int v = (t < NB) ? dstBinCount[t] : 0;
    s[t] = v; __syncthreads();
    for (int off = 1; off < 256; off <<= 1) {
        int u = (t >= off) ? s[t - off] : 0; __syncthreads();
        s[t] += u; __syncthreads();
    }
    if (t < NB) {
        int ex = s[t] - v;
        dstBinBase[t] = ex; dstCursor[t] = ex;
        if (t == NB - 1) dstBinBase[NB] = s[t];
    }
    __syncthreads();
    v = (t < NB) ? srcBinCount[t] : 0;
    s[t] = v; __syncthreads();
    for (int off = 1; off < 256; off <<= 1) {
        int u = (t >= off) ? s[t - off] : 0; __syncthreads();
        s[t] += u; __syncthreads();
    }
    if (t < NB) {
        int ex = s[t] - v;
        srcBinBase[t] = ex; srcCursor[t] = ex;
        if (t == NB - 1) srcBinBase[NB] = s[t];
    }
}

// ---- B: partition edges by dst>>8 and src-lows by src>>8 (LDS ranks) ----
__global__ void partition_kernel(const int* __restrict__ src, const int* __restrict__ dst,
                                 int* __restrict__ dstCursor, int* __restrict__ srcCursor,
                                 int* __restrict__ packed, int* __restrict__ srcPart,
                                 int E, int NB) {
    __shared__ int arr[256];
    int tid = threadIdx.x;
    int base = blockIdx.x * EPB;
    // dst partition
    arr[tid] = 0; __syncthreads();
    #pragma unroll
    for (int it = 0; it < EPB / BS; it++) {
        int e = base + it * BS + tid;
        if (e < E) atomicAdd(&arr[dst[e] >> 8], 1);
    }
    __syncthreads();
    int h = arr[tid];
    int rb = (tid < NB && h) ? atomicAdd(&dstCursor[tid], h) : 0;
    __syncthreads();
    arr[tid] = rb;
    __syncthreads();
    #pragma unroll
    for (int it = 0; it < EPB / BS; it++) {
        int e = base + it * BS + tid;
        if (e < E) {
            int d = dst[e], s2 = src[e];
            int pos = atomicAdd(&arr[d >> 8], 1);
            packed[pos] = s2 | ((d & 255) << 17);
        }
    }
    __syncthreads();
    // src partition (for out_deg counting)
    arr[tid] = 0; __syncthreads();
    #pragma unroll
    for (int it = 0; it < EPB / BS; it++) {
        int e = base + it * BS + tid;
        if (e < E) atomicAdd(&arr[src[e] >> 8], 1);
    }
    __syncthreads();
    h = arr[tid];
    rb = (tid < NB && h) ? atomicAdd(&srcCursor[tid], h) : 0;
    __syncthreads();
    arr[tid] = rb;
    __syncthreads();
    #pragma unroll
    for (int it = 0; it < EPB / BS; it++) {
        int e = base + it * BS + tid;
        if (e < E) {
            int s2 = src[e];
            int pos = atomicAdd(&arr[s2 >> 8], 1);
            srcPart[pos] = s2 & 255;
        }
    }
}

// ---- D: per-bin finalize: in_deg/row_start/csr_src (dst bins);
//          out_deg + featp out_norm pre-scale (src bins) ----
__global__ void finalize_kernel(const int* __restrict__ dstBinBase, const int* __restrict__ srcBinBase,
                                const int* __restrict__ packed, const int* __restrict__ srcPart,
                                int* __restrict__ csr_src, int* __restrict__ in_deg,
                                int* __restrict__ row_start, int* __restrict__ out_deg,
                                __half* __restrict__ featp,
                                int N, int NB) {
    __shared__ int hist[256];
    __shared__ int sc[256];
    int tid = threadIdx.x;
    int b = blockIdx.x;
    if (b < NB) {
        int lo = dstBinBase[b], hi = dstBinBase[b + 1];
        hist[tid] = 0; __syncthreads();
        for (int i = lo + tid; i < hi; i += BS)
            atomicAdd(&hist[(packed[i] >> 17) & 255], 1);
        __syncthreads();
        int v = hist[tid];
        sc[tid] = v; __syncthreads();
        for (int off = 1; off < 256; off <<= 1) {
            int u = (tid >= off) ? sc[tid - off] : 0; __syncthreads();
            sc[tid] += u; __syncthreads();
        }
        int ex = sc[tid] - v;          // exclusive within bin
        int n = b * 256 + tid;
        if (n < N) { in_deg[n] = v; row_start[n] = lo + ex; }
        sc[tid] = lo + ex;             // becomes the scatter cursor
        __syncthreads();
        for (int i = lo + tid; i < hi; i += BS) {
            int pv = packed[i];
            int pos = atomicAdd(&sc[(pv >> 17) & 255], 1);
            csr_src[pos] = pv & 0x1FFFF;
        }
    } else {
        int sb = b - NB;
        int lo = srcBinBase[sb], hi = srcBinBase[sb + 1];
        hist[tid] = 0; __syncthreads();
        for (int i = lo + tid; i < hi; i += BS)
            atomicAdd(&hist[srcPart[i]], 1);
        __syncthreads();
        int n = sb * 256 + tid;
        int od = hist[tid];
        if (n < N) out_deg[n] = od;
        float* snorm = (float*)sc;     // reuse LDS
        snorm[tid] = rsqrtf(fmaxf((float)od, 1.0f));
        __syncthreads();
        // pre-scale featp rows of this bin by out_norm (contiguous 32KB block)
        int nodes = min(256, N - sb * 256);
        uint4* fp = (uint4*)(featp + (size_t)sb * 256 * 64);   // 8 uint4 per row
        int total = nodes * 8;
        for (int i = tid; i < total; i += BS) {
            float s = snorm[i >> 3];   // 8 lanes share a node -> LDS broadcast
            uint4 u = fp[i];
            __half2* hh = (__half2*)&u;
            #pragma unroll
            for (int c = 0; c < 4; c++) {
                float2 p = __half22float2(hh[c]);
                p.x *= s; p.y *= s;
                hh[c] = __float22half2_rn(p);
            }
            fp[i] = u;
        }
    }
}

// ---- agg1: one wave/node; 8 edge-groups x 8 chunks, unroll-2; featp pre-scaled ----
__global__ void csr_agg1_kernel(const int* __restrict__ row_start, const int* __restrict__ in_deg,
                                const int* __restrict__ csr_src, const int* __restrict__ out_deg,
                                const __half* __restrict__ featp,
                                const float* __restrict__ b1, const float* __restrict__ W2,
                                float* __restrict__ s_buf, int N) {
    int gid = blockIdx.x * blockDim.x + threadIdx.x;
    int n = gid >> 6;
    if (n >= N) return;
    int lane = threadIdx.x & 63;
    int g = lane >> 3;   // edge slot within batch of 8
    int l = lane & 7;    // feature chunk: features [8l, 8l+8)
    int start = row_start[n];
    int deg = in_deg[n];
    float acc[8] = {0, 0, 0, 0, 0, 0, 0, 0};
    const uint4* fp4 = (const uint4*)featp;
    for (int j = 0; j < deg; j += 16) {
        int e0 = j + g;
        int e1 = j + 8 + g;
        bool p0 = e0 < deg;
        bool p1 = e1 < deg;
        int sn0 = p0 ? csr_src[start + e0] : 0;
        int sn1 = p1 ? csr_src[start + e1] : 0;
        uint4 q0 = {0, 0, 0, 0}, q1 = {0, 0, 0, 0};
        if (p0) q0 = fp4[(size_t)sn0 * 8 + l];
        if (p1) q1 = fp4[(size_t)sn1 * 8 + l];
        const __half2* h0 = (const __half2*)&q0;
        const __half2* h1 = (const __half2*)&q1;
        #pragma unroll
        for (int c = 0; c < 4; c++) {
            float2 f0 = __half22float2(h0[c]);
            float2 f1 = __half22float2(h1[c]);
            acc[2 * c]     += f0.x + f1.x;
            acc[2 * c + 1] += f0.y + f1.y;
        }
    }
    #pragma unroll
    for (int off = 8; off < 64; off <<= 1) {
        #pragma unroll
        for (int c = 0; c < 8; c++)
            acc[c] += __shfl_xor(acc[c], off, 64);
    }
    float inn = rsqrtf(fmaxf((float)deg, 1.0f));
    float v = 0.0f;
    #pragma unroll
    for (int c = 0; c < 8; c++) {
        float h = fmaxf(inn * acc[c] + b1[l * 8 + c], 0.0f);
        v += h * W2[l * 8 + c];
    }
    #pragma unroll
    for (int off = 1; off < 8; off <<= 1)
        v += __shfl_xor(v, off, 64);
    if (lane == 0)
        s_buf[n] = rsqrtf(fmaxf((float)out_deg[n], 1.0f)) * v;
}

// ---- agg2: 16 lanes/node, unroll-2, sigmoid -> out ----
__global__ void csr_agg2_kernel(const int* __restrict__ row_start, const int* __restrict__ in_deg,
                                const int* __restrict__ csr_src,
                                const float* __restrict__ s_buf, const float* __restrict__ b2,
                                float* __restrict__ out, int N) {
    int gid = blockIdx.x * blockDim.x + threadIdx.x;
    int n = gid >> 4;
    if (n >= N) return;
    int sub = gid & 15;
    int start = row_start[n];
    int deg = in_deg[n];
    float a = 0.0f;
    for (int j = sub; j < deg; j += 32) {
        int j1 = j + 16;
        int i0 = csr_src[start + j];
        int i1 = (j1 < deg) ? csr_src[start + j1] : 0;
        float v0 = s_buf[i0];
        float v1 = (j1 < deg) ? s_buf[i1] : 0.0f;
        a += v0 + v1;
    }
    #pragma unroll
    for (int off = 1; off < 16; off <<= 1)
        a += __shfl_xor(a, off, 64);
    if (sub == 0) {
        float x = rsqrtf(fmaxf((float)deg, 1.0f)) * a + b2[0];
        out[n] = 1.0f / (1.0f + expf(-x));
    }
}

extern "C" void kernel_launch(void* const* d_in, const int* in_sizes, int n_in,
                              void* d_out, int out_size, void* d_ws, size_t ws_size,
                              hipStream_t stream) {
    const float* feat = (const float*)d_in[0];
    const float* W1   = (const float*)d_in[1];
    const float* b1   = (const float*)d_in[2];
    const float* W2   = (const float*)d_in[3];
    const float* b2   = (const float*)d_in[4];
    const int* src = (const int*)d_in[5];
    const int* dst = (const int*)d_in[6];
    float* out = (float*)d_out;

    const int N  = in_sizes[0] / 64;       // 50000
    const int E  = in_sizes[5];            // 800000
    const int NB = (N + 255) >> 8;         // 196 bins of 256 nodes
    const int T  = (E + EPB - 1) / EPB;    // 196 partition blocks

    // workspace: int region | fp16 featp (16B-aligned) | float s_buf
    int* wsi = (int*)d_ws;
    int* dstBinCount = wsi;                          // NB  (zeroed together)
    int* srcBinCount = dstBinCount + NB;             // NB
    int* dstBinBase  = srcBinCount + NB;             // NB+1
    int* srcBinBase  = dstBinBase + NB + 1;          // NB+1
    int* dstCursor   = srcBinBase + NB + 1;          // NB
    int* srcCursor   = dstCursor + NB;               // NB
    int* in_deg      = srcCursor + NB;               // N
    int* row_start   = in_deg + N;                   // N
    int* out_deg     = row_start + N;                // N
    int* packed      = out_deg + N;                  // E
    int* srcPart     = packed + E;                   // E
    int* csr_src     = srcPart + E;                  // E
    size_t int_bytes = ((size_t)(6 * NB + 2) + 3 * (size_t)N + 3 * (size_t)E) * sizeof(int);
    size_t half_off  = (int_bytes + 15) & ~(size_t)15;
    __half* featp = (__half*)((char*)d_ws + half_off);            // 64N fp16
    float* s_buf  = (float*)((char*)d_ws + half_off + (size_t)64 * N * sizeof(__half));

    hipMemsetAsync(dstBinCount, 0, (size_t)2 * NB * sizeof(int), stream);

    histA_featw1_kernel<<<T + (N + 63) / 64, BS, 0, stream>>>(
        src, dst, feat, W1, dstBinCount, srcBinCount, featp, E, N, NB, T);
    scan_bins_kernel<<<1, 256, 0, stream>>>(
        dstBinCount, srcBinCount, dstBinBase, srcBinBase, dstCursor, srcCursor, NB);
    partition_kernel<<<T, BS, 0, stream>>>(
        src, dst, dstCursor, srcCursor, packed, srcPart, E, NB);
    finalize_kernel<<<2 * NB, BS, 0, stream>>>(
        dstBinBase, srcBinBase, packed, srcPart, csr_src, in_deg, row_start, out_deg, featp, N, NB);
    csr_agg1_kernel<<<(int)(((size_t)N * 64 + BS - 1) / BS), BS, 0, stream>>>(
        row_start, in_deg, csr_src, out_deg, featp, b1, W2, s_buf, N);
    csr_agg2_kernel<<<(int)(((size_t)N * 16 + BS - 1) / BS), BS, 0, stream>>>(
        row_start, in_deg, csr_src, s_buf, b2, out, N);
}

// Round 3
// 163.531 us; speedup vs baseline: 2.3411x; 1.6951x over previous
//
#include <hip/hip_runtime.h>
#include <hip/hip_fp16.h>
#include <math.h>

// GCN 2-layer (DGL GraphConv norm='both'). CSR built by a two-level MSD
// counting sort with NO per-edge global atomics.
//   A : per-block LDS hist of dst>>8 and src>>8 (+38k tiny global adds)
//       co-scheduled with featw1 = fp16(feat @ W1), UNNORMALIZED.
//       featw1: W1 column in 64 NAMED scalar VGPRs per lane (static access,
//       cannot go to scratch; __launch_bounds__(256,4) caps VGPR at 128 so
//       the allocator can't repeat the 64-cap spill of rounds 1-2).
//       feat staged via LDS (64 rows/block, 16KB), read as b128 broadcasts:
//       per-row LDS 16 instr (vs round-0's 80 -> that was the 45us bound).
//   C0: 1-block exclusive scan of the 196 bin counts -> bases + cursors
//   B : partition: edges scattered by dst-high (packed src|dstLow<<17, LDS ranks,
//       per-block range reserve), src-low bytes scattered by src-high
//   D : per 256-node bin: LDS hist of low byte -> in_deg, row_start, csr_src
//       scatter; src bins -> out_deg AND pre-scale featp rows by
//       rsqrt(out_deg) (removes per-edge out_deg gather + rsqrt from agg1)
//   agg1: one wave/node, 8 edge-groups x 8 fp16 chunks, unroll-2; features
//         already out_norm-scaled; relu+b1+.W2 epilogue -> s_buf
//   agg2: 16 lanes/node -> sigmoid -> out
// Requires N <= 65536 (src packed into 17 bits, NB <= 256). N=50000 here.

#define BS 256
#define EPB 4096   // edges per partition block (16 iters of 256)

// ---- A: bin histograms + featw1 (independent work co-scheduled) ----
__global__ __launch_bounds__(256, 4)
void histA_featw1_kernel(const int* __restrict__ src, const int* __restrict__ dst,
                         const float* __restrict__ feat, const float* __restrict__ W1,
                         int* __restrict__ dstBinCount, int* __restrict__ srcBinCount,
                         __half* __restrict__ featp,
                         int E, int N, int NB, int T) {
    __shared__ float4 ftile[64 * 16];   // 64 feat rows (16KB)
    __shared__ int histD[256];
    __shared__ int histS[256];
    int tid = threadIdx.x;
    if ((int)blockIdx.x < T) {
        histD[tid] = 0; histS[tid] = 0;
        __syncthreads();
        int base = blockIdx.x * EPB;
        #pragma unroll
        for (int it = 0; it < EPB / BS; it++) {
            int e = base + it * BS + tid;
            if (e < E) {
                atomicAdd(&histD[dst[e] >> 8], 1);
                atomicAdd(&histS[src[e] >> 8], 1);
            }
        }
        __syncthreads();
        if (tid < NB) {
            if (histD[tid]) atomicAdd(&dstBinCount[tid], histD[tid]);
            if (histS[tid]) atomicAdd(&srcBinCount[tid], histS[tid]);
        }
    } else {
        int lane = tid & 63;
        int wave = tid >> 6;
        // W1 column for this lane: 64 named scalars (static -> registers).
        #define WD(i) float wv##i = W1[(i) * 64 + lane];
        WD(0)  WD(1)  WD(2)  WD(3)  WD(4)  WD(5)  WD(6)  WD(7)
        WD(8)  WD(9)  WD(10) WD(11) WD(12) WD(13) WD(14) WD(15)
        WD(16) WD(17) WD(18) WD(19) WD(20) WD(21) WD(22) WD(23)
        WD(24) WD(25) WD(26) WD(27) WD(28) WD(29) WD(30) WD(31)
        WD(32) WD(33) WD(34) WD(35) WD(36) WD(37) WD(38) WD(39)
        WD(40) WD(41) WD(42) WD(43) WD(44) WD(45) WD(46) WD(47)
        WD(48) WD(49) WD(50) WD(51) WD(52) WD(53) WD(54) WD(55)
        WD(56) WD(57) WD(58) WD(59) WD(60) WD(61) WD(62) WD(63)
        #undef WD
        // stage 64 feat rows into LDS (coalesced, 4 float4/thread)
        int rBase = ((int)blockIdx.x - T) * 64;
        const float4* feat4 = (const float4*)feat;
        int maxF4 = N * 16 - 1;
        #pragma unroll
        for (int it = 0; it < 4; it++) {
            int idx = it * BS + tid;
            ftile[idx] = feat4[min(rBase * 16 + idx, maxF4)];
        }
        __syncthreads();
        // 16 rows per wave; per row: 16 b128 broadcast reads + 64 FMA
        #pragma unroll 1
        for (int rr = 0; rr < 16; rr++) {
            int r = wave * 16 + rr;
            const float4* ft = &ftile[r * 16];
            float a0 = 0.0f, a1 = 0.0f, a2 = 0.0f, a3 = 0.0f;
            #define RK(k4, wA, wB, wC, wD_) { float4 f = ft[k4]; \
                a0 = fmaf(f.x, wA, a0); a1 = fmaf(f.y, wB, a1); \
                a2 = fmaf(f.z, wC, a2); a3 = fmaf(f.w, wD_, a3); }
            RK(0,  wv0,  wv1,  wv2,  wv3)  RK(1,  wv4,  wv5,  wv6,  wv7)
            RK(2,  wv8,  wv9,  wv10, wv11) RK(3,  wv12, wv13, wv14, wv15)
            RK(4,  wv16, wv17, wv18, wv19) RK(5,  wv20, wv21, wv22, wv23)
            RK(6,  wv24, wv25, wv26, wv27) RK(7,  wv28, wv29, wv30, wv31)
            RK(8,  wv32, wv33, wv34, wv35) RK(9,  wv36, wv37, wv38, wv39)
            RK(10, wv40, wv41, wv42, wv43) RK(11, wv44, wv45, wv46, wv47)
            RK(12, wv48, wv49, wv50, wv51) RK(13, wv52, wv53, wv54, wv55)
            RK(14, wv56, wv57, wv58, wv59) RK(15, wv60, wv61, wv62, wv63)
            #undef RK
            int rowg = rBase + r;
            if (rowg < N)
                featp[(size_t)rowg * 64 + lane] = __float2half((a0 + a1) + (a2 + a3));
        }
    }
}

// ---- C0: scan both 196-bin count arrays (tiny, 1 block) ----
__global__ void scan_bins_kernel(const int* __restrict__ dstBinCount, const int* __restrict__ srcBinCount,
                                 int* __restrict__ dstBinBase, int* __restrict__ srcBinBase,
                                 int* __restrict__ dstCursor, int* __restrict__ srcCursor, int NB) {
    __shared__ int s[256];
    int t = threadIdx.x;
    int v = (t < NB) ? dstBinCount[t] : 0;
    s[t] = v; __syncthreads();
    for (int off = 1; off < 256; off <<= 1) {
        int u = (t >= off) ? s[t - off] : 0; __syncthreads();
        s[t] += u; __syncthreads();
    }
    if (t < NB) {
        int ex = s[t] - v;
        dstBinBase[t] = ex; dstCursor[t] = ex;
        if (t == NB - 1) dstBinBase[NB] = s[t];
    }
    __syncthreads();
    v = (t < NB) ? srcBinCount[t] : 0;
    s[t] = v; __syncthreads();
    for (int off = 1; off < 256; off <<= 1) {
        int u = (t >= off) ? s[t - off] : 0; __syncthreads();
        s[t] += u; __syncthreads();
    }
    if (t < NB) {
        int ex = s[t] - v;
        srcBinBase[t] = ex; srcCursor[t] = ex;
        if (t == NB - 1) srcBinBase[NB] = s[t];
    }
}

// ---- B: partition edges by dst>>8 and src-lows by src>>8 (LDS ranks) ----
__global__ void partition_kernel(const int* __restrict__ src, const int* __restrict__ dst,
                                 int* __restrict__ dstCursor, int* __restrict__ srcCursor,
                                 int* __restrict__ packed, int* __restrict__ srcPart,
                                 int E, int NB) {
    __shared__ int arr[256];
    int tid = threadIdx.x;
    int base = blockIdx.x * EPB;
    // dst partition
    arr[tid] = 0; __syncthreads();
    #pragma unroll
    for (int it = 0; it < EPB / BS; it++) {
        int e = base + it * BS + tid;
        if (e < E) atomicAdd(&arr[dst[e] >> 8], 1);
    }
    __syncthreads();
    int h = arr[tid];
    int rb = (tid < NB && h) ? atomicAdd(&dstCursor[tid], h) : 0;
    __syncthreads();
    arr[tid] = rb;
    __syncthreads();
    #pragma unroll
    for (int it = 0; it < EPB / BS; it++) {
        int e = base + it * BS + tid;
        if (e < E) {
            int d = dst[e], s2 = src[e];
            int pos = atomicAdd(&arr[d >> 8], 1);
            packed[pos] = s2 | ((d & 255) << 17);
        }
    }
    __syncthreads();
    // src partition (for out_deg counting)
    arr[tid] = 0; __syncthreads();
    #pragma unroll
    for (int it = 0; it < EPB / BS; it++) {
        int e = base + it * BS + tid;
        if (e < E) atomicAdd(&arr[src[e] >> 8], 1);
    }
    __syncthreads();
    h = arr[tid];
    rb = (tid < NB && h) ? atomicAdd(&srcCursor[tid], h) : 0;
    __syncthreads();
    arr[tid] = rb;
    __syncthreads();
    #pragma unroll
    for (int it = 0; it < EPB / BS; it++) {
        int e = base + it * BS + tid;
        if (e < E) {
            int s2 = src[e];
            int pos = atomicAdd(&arr[s2 >> 8], 1);
            srcPart[pos] = s2 & 255;
        }
    }
}

// ---- D: per-bin finalize: in_deg/row_start/csr_src (dst bins);
//          out_deg + featp out_norm pre-scale (src bins) ----
__global__ void finalize_kernel(const int* __restrict__ dstBinBase, const int* __restrict__ srcBinBase,
                                const int* __restrict__ packed, const int* __restrict__ srcPart,
                                int* __restrict__ csr_src, int* __restrict__ in_deg,
                                int* __restrict__ row_start, int* __restrict__ out_deg,
                                __half* __restrict__ featp,
                                int N, int NB) {
    __shared__ int hist[256];
    __shared__ int sc[256];
    int tid = threadIdx.x;
    int b = blockIdx.x;
    if (b < NB) {
        int lo = dstBinBase[b], hi = dstBinBase[b + 1];
        hist[tid] = 0; __syncthreads();
        for (int i = lo + tid; i < hi; i += BS)
            atomicAdd(&hist[(packed[i] >> 17) & 255], 1);
        __syncthreads();
        int v = hist[tid];
        sc[tid] = v; __syncthreads();
        for (int off = 1; off < 256; off <<= 1) {
            int u = (tid >= off) ? sc[tid - off] : 0; __syncthreads();
            sc[tid] += u; __syncthreads();
        }
        int ex = sc[tid] - v;          // exclusive within bin
        int n = b * 256 + tid;
        if (n < N) { in_deg[n] = v; row_start[n] = lo + ex; }
        sc[tid] = lo + ex;             // becomes the scatter cursor
        __syncthreads();
        for (int i = lo + tid; i < hi; i += BS) {
            int pv = packed[i];
            int pos = atomicAdd(&sc[(pv >> 17) & 255], 1);
            csr_src[pos] = pv & 0x1FFFF;
        }
    } else {
        int sb = b - NB;
        int lo = srcBinBase[sb], hi = srcBinBase[sb + 1];
        hist[tid] = 0; __syncthreads();
        for (int i = lo + tid; i < hi; i += BS)
            atomicAdd(&hist[srcPart[i]], 1);
        __syncthreads();
        int n = sb * 256 + tid;
        int od = hist[tid];
        if (n < N) out_deg[n] = od;
        float* snorm = (float*)sc;     // reuse LDS
        snorm[tid] = rsqrtf(fmaxf((float)od, 1.0f));
        __syncthreads();
        // pre-scale featp rows of this bin by out_norm (contiguous 32KB block)
        int nodes = min(256, N - sb * 256);
        uint4* fp = (uint4*)(featp + (size_t)sb * 256 * 64);   // 8 uint4 per row
        int total = nodes * 8;
        for (int i = tid; i < total; i += BS) {
            float s = snorm[i >> 3];   // 8 lanes share a node -> LDS broadcast
            uint4 u = fp[i];
            __half2* hh = (__half2*)&u;
            #pragma unroll
            for (int c = 0; c < 4; c++) {
                float2 p = __half22float2(hh[c]);
                p.x *= s; p.y *= s;
                hh[c] = __float22half2_rn(p);
            }
            fp[i] = u;
        }
    }
}

// ---- agg1: one wave/node; 8 edge-groups x 8 chunks, unroll-2; featp pre-scaled ----
__global__ void csr_agg1_kernel(const int* __restrict__ row_start, const int* __restrict__ in_deg,
                                const int* __restrict__ csr_src, const int* __restrict__ out_deg,
                                const __half* __restrict__ featp,
                                const float* __restrict__ b1, const float* __restrict__ W2,
                                float* __restrict__ s_buf, int N) {
    int gid = blockIdx.x * blockDim.x + threadIdx.x;
    int n = gid >> 6;
    if (n >= N) return;
    int lane = threadIdx.x & 63;
    int g = lane >> 3;   // edge slot within batch of 8
    int l = lane & 7;    // feature chunk: features [8l, 8l+8)
    int start = row_start[n];
    int deg = in_deg[n];
    float acc[8] = {0, 0, 0, 0, 0, 0, 0, 0};
    const uint4* fp4 = (const uint4*)featp;
    for (int j = 0; j < deg; j += 16) {
        int e0 = j + g;
        int e1 = j + 8 + g;
        bool p0 = e0 < deg;
        bool p1 = e1 < deg;
        int sn0 = p0 ? csr_src[start + e0] : 0;
        int sn1 = p1 ? csr_src[start + e1] : 0;
        uint4 q0 = {0, 0, 0, 0}, q1 = {0, 0, 0, 0};
        if (p0) q0 = fp4[(size_t)sn0 * 8 + l];
        if (p1) q1 = fp4[(size_t)sn1 * 8 + l];
        const __half2* h0 = (const __half2*)&q0;
        const __half2* h1 = (const __half2*)&q1;
        #pragma unroll
        for (int c = 0; c < 4; c++) {
            float2 f0 = __half22float2(h0[c]);
            float2 f1 = __half22float2(h1[c]);
            acc[2 * c]     += f0.x + f1.x;
            acc[2 * c + 1] += f0.y + f1.y;
        }
    }
    #pragma unroll
    for (int off = 8; off < 64; off <<= 1) {
        #pragma unroll
        for (int c = 0; c < 8; c++)
            acc[c] += __shfl_xor(acc[c], off, 64);
    }
    float inn = rsqrtf(fmaxf((float)deg, 1.0f));
    float v = 0.0f;
    #pragma unroll
    for (int c = 0; c < 8; c++) {
        float h = fmaxf(inn * acc[c] + b1[l * 8 + c], 0.0f);
        v += h * W2[l * 8 + c];
    }
    #pragma unroll
    for (int off = 1; off < 8; off <<= 1)
        v += __shfl_xor(v, off, 64);
    if (lane == 0)
        s_buf[n] = rsqrtf(fmaxf((float)out_deg[n], 1.0f)) * v;
}

// ---- agg2: 16 lanes/node, unroll-2, sigmoid -> out ----
__global__ void csr_agg2_kernel(const int* __restrict__ row_start, const int* __restrict__ in_deg,
                                const int* __restrict__ csr_src,
                                const float* __restrict__ s_buf, const float* __restrict__ b2,
                                float* __restrict__ out, int N) {
    int gid = blockIdx.x * blockDim.x + threadIdx.x;
    int n = gid >> 4;
    if (n >= N) return;
    int sub = gid & 15;
    int start = row_start[n];
    int deg = in_deg[n];
    float a = 0.0f;
    for (int j = sub; j < deg; j += 32) {
        int j1 = j + 16;
        int i0 = csr_src[start + j];
        int i1 = (j1 < deg) ? csr_src[start + j1] : 0;
        float v0 = s_buf[i0];
        float v1 = (j1 < deg) ? s_buf[i1] : 0.0f;
        a += v0 + v1;
    }
    #pragma unroll
    for (int off = 1; off < 16; off <<= 1)
        a += __shfl_xor(a, off, 64);
    if (sub == 0) {
        float x = rsqrtf(fmaxf((float)deg, 1.0f)) * a + b2[0];
        out[n] = 1.0f / (1.0f + expf(-x));
    }
}

extern "C" void kernel_launch(void* const* d_in, const int* in_sizes, int n_in,
                              void* d_out, int out_size, void* d_ws, size_t ws_size,
                              hipStream_t stream) {
    const float* feat = (const float*)d_in[0];
    const float* W1   = (const float*)d_in[1];
    const float* b1   = (const float*)d_in[2];
    const float* W2   = (const float*)d_in[3];
    const float* b2   = (const float*)d_in[4];
    const int* src = (const int*)d_in[5];
    const int* dst = (const int*)d_in[6];
    float* out = (float*)d_out;

    const int N  = in_sizes[0] / 64;       // 50000
    const int E  = in_sizes[5];            // 800000
    const int NB = (N + 255) >> 8;         // 196 bins of 256 nodes
    const int T  = (E + EPB - 1) / EPB;    // 196 partition blocks

    // workspace: int region | fp16 featp (16B-aligned) | float s_buf
    int* wsi = (int*)d_ws;
    int* dstBinCount = wsi;                          // NB  (zeroed together)
    int* srcBinCount = dstBinCount + NB;             // NB
    int* dstBinBase  = srcBinCount + NB;             // NB+1
    int* srcBinBase  = dstBinBase + NB + 1;          // NB+1
    int* dstCursor   = srcBinBase + NB + 1;          // NB
    int* srcCursor   = dstCursor + NB;               // NB
    int* in_deg      = srcCursor + NB;               // N
    int* row_start   = in_deg + N;                   // N
    int* out_deg     = row_start + N;                // N
    int* packed      = out_deg + N;                  // E
    int* srcPart     = packed + E;                   // E
    int* csr_src     = srcPart + E;                  // E
    size_t int_bytes = ((size_t)(6 * NB + 2) + 3 * (size_t)N + 3 * (size_t)E) * sizeof(int);
    size_t half_off  = (int_bytes + 15) & ~(size_t)15;
    __half* featp = (__half*)((char*)d_ws + half_off);            // 64N fp16
    float* s_buf  = (float*)((char*)d_ws + half_off + (size_t)64 * N * sizeof(__half));

    hipMemsetAsync(dstBinCount, 0, (size_t)2 * NB * sizeof(int), stream);

    histA_featw1_kernel<<<T + (N + 63) / 64, BS, 0, stream>>>(
        src, dst, feat, W1, dstBinCount, srcBinCount, featp, E, N, NB, T);
    scan_bins_kernel<<<1, 256, 0, stream>>>(
        dstBinCount, srcBinCount, dstBinBase, srcBinBase, dstCursor, srcCursor, NB);
    partition_kernel<<<T, BS, 0, stream>>>(
        src, dst, dstCursor, srcCursor, packed, srcPart, E, NB);
    finalize_kernel<<<2 * NB, BS, 0, stream>>>(
        dstBinBase, srcBinBase, packed, srcPart, csr_src, in_deg, row_start, out_deg, featp, N, NB);
    csr_agg1_kernel<<<(int)(((size_t)N * 64 + BS - 1) / BS), BS, 0, stream>>>(
        row_start, in_deg, csr_src, out_deg, featp, b1, W2, s_buf, N);
    csr_agg2_kernel<<<(int)(((size_t)N * 16 + BS - 1) / BS), BS, 0, stream>>>(
        row_start, in_deg, csr_src, s_buf, b2, out, N);
}